// Round 2
// 489.621 us; speedup vs baseline: 1.0127x; 1.0127x over previous
//
#include <hip/hip_runtime.h>
#include <math.h>

#define BATCH 16
#define NH 32
#define KVH 8
#define NREP 4
#define HD 128
#define BS 16
#define BPS 256
#define MAXSEQ 4096
#define NSPLITS 32
#define ATT_SCALE 0.08838834764831845f
#define REC (NREP * HD + 2 * NREP) /* 520 floats per partial record (2080 B, 16B-aligned) */

// ---------------------------------------------------------------------------
// 16-lane rotation reduce on the VALU pipe (DPP row_ror) — no LDS ops.
// After 4 steps every lane of the 16-lane row holds the full row sum.
// ---------------------------------------------------------------------------
__device__ __forceinline__ float rowsum16(float x) {
  int t;
  t = __builtin_amdgcn_update_dpp(0, __float_as_int(x), 0x121, 0xf, 0xf, true); // row_ror:1
  x += __int_as_float(t);
  t = __builtin_amdgcn_update_dpp(0, __float_as_int(x), 0x122, 0xf, 0xf, true); // row_ror:2
  x += __int_as_float(t);
  t = __builtin_amdgcn_update_dpp(0, __float_as_int(x), 0x124, 0xf, 0xf, true); // row_ror:4
  x += __int_as_float(t);
  t = __builtin_amdgcn_update_dpp(0, __float_as_int(x), 0x128, 0xf, 0xf, true); // row_ror:8
  x += __int_as_float(t);
  return x;
}

// ---------------------------------------------------------------------------
// Kernel 1: scatter new K/V tokens into the flat-slot view of the caches.
// ---------------------------------------------------------------------------
__global__ __launch_bounds__(256) void kv_scatter(
    const float* __restrict__ k, const float* __restrict__ v,
    const int* __restrict__ slot_mapping,
    float* __restrict__ k_cache, float* __restrict__ v_cache) {
  int b = blockIdx.x;
  int slot = slot_mapping[b];
  size_t base = (size_t)slot * (KVH * HD) + threadIdx.x * 4;
  size_t src = (size_t)b * (KVH * HD) + threadIdx.x * 4;
  *(float4*)(k_cache + base) = *(const float4*)(k + src);
  *(float4*)(v_cache + base) = *(const float4*)(v + src);
}

// ---------------------------------------------------------------------------
// Kernel 2: flash-decode. grid = (NSPLITS/4, KVH, BATCH), 256 threads.
// Wave w of a block owns split blockIdx.x*4+w — waves are FULLY independent:
// no LDS, no barriers. Lane = 16*g + d16: group g owns tokens t≡g (mod 4),
// dim-slice d16 covers dims [d16*8, d16*8+8). Per-group private online
// softmax; groups merged once at the end via 2-step xor shuffles.
//
// DYNAMIC SPANS: instead of a fixed 128-token span against MAXSEQ (which
// idles ~half the waves for random ctx), each (b,kvh) divides its ACTUAL
// context evenly over all 32 splits in 16-token cache-block units. All
// 4096 waves stay active (4/SIMD) and per-wave serial depth halves.
// ---------------------------------------------------------------------------
__global__ __launch_bounds__(256, 4) void attn_decode(
    const float* __restrict__ q,
    const float* __restrict__ k_cache,
    const float* __restrict__ v_cache,
    const int* __restrict__ block_tables,
    const int* __restrict__ context_lens,
    float* __restrict__ part) {   // [B][KVH][NSPLITS][REC]
  const int tid  = threadIdx.x;
  const int wave = tid >> 6;
  const int lane = tid & 63;
  const int g    = lane >> 4;
  const int d16  = lane & 15;
  const int kvh  = blockIdx.y;
  const int b    = blockIdx.z;
  const int split = blockIdx.x * 4 + wave;
  const int ctx  = context_lens[b];

  float* rec = part + (((size_t)b * KVH + kvh) * NSPLITS + split) * REC;

  // Even division of this sequence's cache blocks over the 32 splits.
  const int nbt = (ctx + BS - 1) >> 4;                 // total 16-token blocks
  const int psp = (nbt + NSPLITS - 1) / NSPLITS;       // blocks per split (1..8)
  const int cb0 = split * psp;

  if (cb0 >= nbt) {
    if (lane < NREP) {
      rec[NREP * HD + lane] = -INFINITY;   // m
      rec[NREP * HD + NREP + lane] = 0.f;  // l
    }
    return;
  }
  const int cb1 = min(nbt, cb0 + psp);
  const int nb  = cb1 - cb0;
  const int s_begin = cb0 << 4;
  const int s_end   = min(ctx, cb1 << 4);

  // Q fragments: 4 heads x 8 dims, per lane (32 floats in VGPRs).
  float4 qa[NREP], qb[NREP];
  const float* qp = q + ((size_t)b * NH + kvh * NREP) * HD + d16 * 8;
#pragma unroll
  for (int h = 0; h < NREP; ++h) {
    qa[h] = *(const float4*)(qp + h * HD);
    qb[h] = *(const float4*)(qp + h * HD + 4);
  }

  float m[NREP], l[NREP], acc[NREP][8];
#pragma unroll
  for (int h = 0; h < NREP; ++h) {
    m[h] = -INFINITY;
    l[h] = 0.f;
#pragma unroll
    for (int j = 0; j < 8; ++j) acc[h][j] = 0.f;
  }

  const int* bt = block_tables + b * BPS + cb0;
  const size_t hoff = (size_t)kvh * HD + d16 * 8;

  // Block-index lookahead: bt[cb+1] is fetched while cb is being processed,
  // so the next iteration's vector loads don't wait on a fresh scalar load.
  int blk = bt[0];
  for (int cb = 0; cb < nb; ++cb) {
    const int blk_next = (cb + 1 < nb) ? bt[cb + 1] : 0;
    const size_t pbase = (size_t)blk * BS * (KVH * HD) + hoff;
    const int tbase = s_begin + cb * BS;
#pragma unroll
    for (int i = 0; i < 4; ++i) {
      const int to = i * 4 + g;   // token within the 16-token cache block
      const float* kp = k_cache + pbase + (size_t)to * (KVH * HD);
      const float* vp = v_cache + pbase + (size_t)to * (KVH * HD);
      float4 ka = *(const float4*)kp;
      float4 kb = *(const float4*)(kp + 4);
      float4 va = *(const float4*)vp;
      float4 vb = *(const float4*)(vp + 4);
      const bool valid = (tbase + to) < s_end;
#pragma unroll
      for (int h = 0; h < NREP; ++h) {
        float s = ka.x * qa[h].x + ka.y * qa[h].y + ka.z * qa[h].z + ka.w * qa[h].w
                + kb.x * qb[h].x + kb.y * qb[h].y + kb.z * qb[h].z + kb.w * qb[h].w;
        s = rowsum16(s) * ATT_SCALE;   // all 16 lanes of the group get the sum
        s = valid ? s : -INFINITY;
        if (s > m[h]) {                // group-uniform branch; rare after warmup
          float alpha = __expf(m[h] - s);  // exp(-inf)=0 handles first token
          l[h] *= alpha;
#pragma unroll
          for (int j = 0; j < 8; ++j) acc[h][j] *= alpha;
          m[h] = s;
        }
        float p = valid ? __expf(s - m[h]) : 0.f;
        l[h] += p;
        acc[h][0] += p * va.x; acc[h][1] += p * va.y;
        acc[h][2] += p * va.z; acc[h][3] += p * va.w;
        acc[h][4] += p * vb.x; acc[h][5] += p * vb.y;
        acc[h][6] += p * vb.z; acc[h][7] += p * vb.w;
      }
    }
    blk = blk_next;
  }

  // ---- Merge the 4 groups (lanes differing in bits 4-5) and emit partials.
#pragma unroll
  for (int h = 0; h < NREP; ++h) {
    float M = m[h];
    M = fmaxf(M, __shfl_xor(M, 16));
    M = fmaxf(M, __shfl_xor(M, 32));
    float w = (m[h] == -INFINITY) ? 0.f : __expf(m[h] - M);
    float lw = l[h] * w;
    lw += __shfl_xor(lw, 16);
    lw += __shfl_xor(lw, 32);
#pragma unroll
    for (int j = 0; j < 8; ++j) {
      float a = acc[h][j] * w;
      a += __shfl_xor(a, 16);
      a += __shfl_xor(a, 32);
      acc[h][j] = a;
    }
    if (lane == 0) {
      rec[NREP * HD + h] = M;          // finite: wave has >=1 valid token
      rec[NREP * HD + NREP + h] = lw;
    }
    if (g == 0) {                      // 16 lanes cover this head's 128 dims
      float* rp = rec + h * HD + d16 * 8;
      *(float4*)rp = make_float4(acc[h][0], acc[h][1], acc[h][2], acc[h][3]);
      *(float4*)(rp + 4) = make_float4(acc[h][4], acc[h][5], acc[h][6], acc[h][7]);
    }
  }
}

// ---------------------------------------------------------------------------
// Kernel 3: merge split partials. grid = (KVH, BATCH), block = 256.
// ---------------------------------------------------------------------------
__global__ __launch_bounds__(256) void attn_combine(
    const float* __restrict__ part, float* __restrict__ out) {
  const int kvh = blockIdx.x;
  const int b   = blockIdx.y;
  const int tid = threadIdx.x;
  const float* base = part + ((size_t)b * KVH + kvh) * NSPLITS * REC;

  __shared__ float w_sh[NSPLITS][NREP];
  __shared__ float L_sh[NREP];

  if (tid < NREP) {
    const int h = tid;
    float M = -INFINITY;
    for (int s = 0; s < NSPLITS; ++s)
      M = fmaxf(M, base[s * REC + NREP * HD + h]);
    float L = 0.f;
    for (int s = 0; s < NSPLITS; ++s) {
      float m = base[s * REC + NREP * HD + h];
      float l = base[s * REC + NREP * HD + NREP + h];
      float w = (l > 0.f) ? __expf(m - M) : 0.f;
      w_sh[s][h] = w;
      L += l * w;
    }
    L_sh[h] = L;
  }
  __syncthreads();

  for (int o = tid; o < NREP * HD; o += 256) {
    int h = o >> 7, d = o & 127;
    float s = 0.f;
    for (int sp = 0; sp < NSPLITS; ++sp) {
      float w = w_sh[sp][h];
      if (w > 0.f) s += w * base[sp * REC + o];
    }
    out[((size_t)b * NH + kvh * NREP + h) * HD + d] = s / L_sh[h];
  }
}

// ---------------------------------------------------------------------------
extern "C" void kernel_launch(void* const* d_in, const int* in_sizes, int n_in,
                              void* d_out, int out_size, void* d_ws, size_t ws_size,
                              hipStream_t stream) {
  const float* q = (const float*)d_in[0];
  const float* k = (const float*)d_in[1];
  const float* v = (const float*)d_in[2];
  float* k_cache = (float*)d_in[3];  // mutated; harness restores before each run
  float* v_cache = (float*)d_in[4];
  const int* block_tables = (const int*)d_in[5];
  const int* context_lens = (const int*)d_in[6];
  const int* slot_mapping = (const int*)d_in[7];
  float* out  = (float*)d_out;
  float* part = (float*)d_ws;   // needs 16*8*32*520*4 = 8.5 MB

  kv_scatter<<<BATCH, 256, 0, stream>>>(k, v, slot_mapping, k_cache, v_cache);

  dim3 grid(NSPLITS / 4, KVH, BATCH);
  attn_decode<<<grid, 256, 0, stream>>>(q, k_cache, v_cache, block_tables,
                                        context_lens, part);
  attn_combine<<<dim3(KVH, BATCH), 256, 0, stream>>>(part, out);
}

// Round 3
// 484.200 us; speedup vs baseline: 1.0240x; 1.0112x over previous
//
#include <hip/hip_runtime.h>
#include <math.h>

#define BATCH 16
#define NH 32
#define KVH 8
#define NREP 4
#define HD 128
#define BS 16
#define BPS 256
#define MAXSEQ 4096
#define NSPLITS 32
#define ATT_SCALE 0.08838834764831845f
#define REC (NREP * HD + 2 * NREP) /* 520 floats per partial record (2080 B, 16B-aligned) */

// ---------------------------------------------------------------------------
// 16-lane rotation reduce on the VALU pipe (DPP row_ror) — no LDS ops.
// After 4 steps every lane of the 16-lane row holds the full row sum.
// ---------------------------------------------------------------------------
__device__ __forceinline__ float rowsum16(float x) {
  int t;
  t = __builtin_amdgcn_update_dpp(0, __float_as_int(x), 0x121, 0xf, 0xf, true); // row_ror:1
  x += __int_as_float(t);
  t = __builtin_amdgcn_update_dpp(0, __float_as_int(x), 0x122, 0xf, 0xf, true); // row_ror:2
  x += __int_as_float(t);
  t = __builtin_amdgcn_update_dpp(0, __float_as_int(x), 0x124, 0xf, 0xf, true); // row_ror:4
  x += __int_as_float(t);
  t = __builtin_amdgcn_update_dpp(0, __float_as_int(x), 0x128, 0xf, 0xf, true); // row_ror:8
  x += __int_as_float(t);
  return x;
}

// ---------------------------------------------------------------------------
// Flash-decode with VIRTUAL KV-scatter. grid = (NSPLITS/4, KVH, BATCH), 256 thr.
// The caches are READ-ONLY: instead of scattering the 16 new K/V tokens into
// the caches (which forces the harness to restore 512 MB before every run),
// decode patches the loaded K/V in-register whenever the cache block being
// read is the home of some slot_mapping[bb]. The check is 16 wave-uniform
// SALU compares per 16-token cache block (ovmask==0 fast path ~98%).
//
// Wave w of a block owns split blockIdx.x*4+w — waves are FULLY independent:
// no LDS, no barriers. Lane = 16*g + d16: group g owns tokens t≡g (mod 4),
// dim-slice d16 covers dims [d16*8, d16*8+8). Per-group private online
// softmax; groups merged once at the end via 2-step xor shuffles.
// Dynamic spans: each (b,kvh) divides its actual context evenly over all
// 32 splits in 16-token cache-block units.
// ---------------------------------------------------------------------------
__global__ __launch_bounds__(256, 4) void attn_decode(
    const float* __restrict__ q,
    const float* __restrict__ k_new,
    const float* __restrict__ v_new,
    const float* __restrict__ k_cache,
    const float* __restrict__ v_cache,
    const int* __restrict__ block_tables,
    const int* __restrict__ context_lens,
    const int* __restrict__ slot_mapping,
    float* __restrict__ part) {   // [B][KVH][NSPLITS][REC]
  const int tid  = threadIdx.x;
  const int wave = tid >> 6;
  const int lane = tid & 63;
  const int g    = lane >> 4;
  const int d16  = lane & 15;
  const int kvh  = blockIdx.y;
  const int b    = blockIdx.z;
  const int split = blockIdx.x * 4 + wave;
  const int ctx  = context_lens[b];

  float* rec = part + (((size_t)b * KVH + kvh) * NSPLITS + split) * REC;

  // Even division of this sequence's cache blocks over the 32 splits.
  const int nbt = (ctx + BS - 1) >> 4;                 // total 16-token blocks
  const int psp = (nbt + NSPLITS - 1) / NSPLITS;       // blocks per split (1..8)
  const int cb0 = split * psp;

  if (cb0 >= nbt) {
    if (lane < NREP) {
      rec[NREP * HD + lane] = -INFINITY;   // m
      rec[NREP * HD + NREP + lane] = 0.f;  // l
    }
    return;
  }
  const int cb1 = min(nbt, cb0 + psp);
  const int nb  = cb1 - cb0;
  const int s_begin = cb0 << 4;
  const int s_end   = min(ctx, cb1 << 4);

  // slot_mapping in scalar regs (uniform): home block + token of each new KV.
  int sslot[BATCH];
#pragma unroll
  for (int bb = 0; bb < BATCH; ++bb) sslot[bb] = slot_mapping[bb];

  // Q fragments: 4 heads x 8 dims, per lane (32 floats in VGPRs).
  float4 qa[NREP], qb[NREP];
  const float* qp = q + ((size_t)b * NH + kvh * NREP) * HD + d16 * 8;
#pragma unroll
  for (int h = 0; h < NREP; ++h) {
    qa[h] = *(const float4*)(qp + h * HD);
    qb[h] = *(const float4*)(qp + h * HD + 4);
  }

  float m[NREP], l[NREP], acc[NREP][8];
#pragma unroll
  for (int h = 0; h < NREP; ++h) {
    m[h] = -INFINITY;
    l[h] = 0.f;
#pragma unroll
    for (int j = 0; j < 8; ++j) acc[h][j] = 0.f;
  }

  const int* bt = block_tables + b * BPS + cb0;
  const size_t hoff = (size_t)kvh * HD + d16 * 8;

  // Block-index lookahead: bt[cb+1] is fetched while cb is being processed.
  int blk = bt[0];
  for (int cb = 0; cb < nb; ++cb) {
    const int blk_next = (cb + 1 < nb) ? bt[cb + 1] : 0;
    const size_t pbase = (size_t)blk * BS * (KVH * HD) + hoff;
    const int tbase = s_begin + cb * BS;

    // Which new-KV slots live in this cache block? (wave-uniform SALU)
    unsigned ovmask = 0u;
#pragma unroll
    for (int bb = 0; bb < BATCH; ++bb)
      if ((sslot[bb] >> 4) == blk) ovmask |= (1u << bb);

#pragma unroll
    for (int i = 0; i < 4; ++i) {
      const int to = i * 4 + g;   // token within the 16-token cache block
      const float* kp = k_cache + pbase + (size_t)to * (KVH * HD);
      const float* vp = v_cache + pbase + (size_t)to * (KVH * HD);
      float4 ka = *(const float4*)kp;
      float4 kb = *(const float4*)(kp + 4);
      float4 va = *(const float4*)vp;
      float4 vb = *(const float4*)(vp + 4);

      if (__builtin_expect(ovmask != 0, 0)) {
        // Rare slow path: replace this token's K/V with the fresh values.
        // Ascending bb with overwrite == "last writer wins" on collisions.
        unsigned mm = ovmask;
        while (mm) {
          const int bb = __ffs(mm) - 1;
          mm &= mm - 1;
          if ((sslot[bb] & 15) == to) {
            const float* nk = k_new + ((size_t)bb * KVH + kvh) * HD + d16 * 8;
            const float* nv = v_new + ((size_t)bb * KVH + kvh) * HD + d16 * 8;
            ka = *(const float4*)nk;
            kb = *(const float4*)(nk + 4);
            va = *(const float4*)nv;
            vb = *(const float4*)(nv + 4);
          }
        }
      }

      const bool valid = (tbase + to) < s_end;
#pragma unroll
      for (int h = 0; h < NREP; ++h) {
        float s = ka.x * qa[h].x + ka.y * qa[h].y + ka.z * qa[h].z + ka.w * qa[h].w
                + kb.x * qb[h].x + kb.y * qb[h].y + kb.z * qb[h].z + kb.w * qb[h].w;
        s = rowsum16(s) * ATT_SCALE;   // all 16 lanes of the group get the sum
        s = valid ? s : -INFINITY;
        if (s > m[h]) {                // group-uniform branch; rare after warmup
          float alpha = __expf(m[h] - s);  // exp(-inf)=0 handles first token
          l[h] *= alpha;
#pragma unroll
          for (int j = 0; j < 8; ++j) acc[h][j] *= alpha;
          m[h] = s;
        }
        float p = valid ? __expf(s - m[h]) : 0.f;
        l[h] += p;
        acc[h][0] += p * va.x; acc[h][1] += p * va.y;
        acc[h][2] += p * va.z; acc[h][3] += p * va.w;
        acc[h][4] += p * vb.x; acc[h][5] += p * vb.y;
        acc[h][6] += p * vb.z; acc[h][7] += p * vb.w;
      }
    }
    blk = blk_next;
  }

  // ---- Merge the 4 groups (lanes differing in bits 4-5) and emit partials.
#pragma unroll
  for (int h = 0; h < NREP; ++h) {
    float M = m[h];
    M = fmaxf(M, __shfl_xor(M, 16));
    M = fmaxf(M, __shfl_xor(M, 32));
    float w = (m[h] == -INFINITY) ? 0.f : __expf(m[h] - M);
    float lw = l[h] * w;
    lw += __shfl_xor(lw, 16);
    lw += __shfl_xor(lw, 32);
#pragma unroll
    for (int j = 0; j < 8; ++j) {
      float a = acc[h][j] * w;
      a += __shfl_xor(a, 16);
      a += __shfl_xor(a, 32);
      acc[h][j] = a;
    }
    if (lane == 0) {
      rec[NREP * HD + h] = M;          // finite: wave has >=1 valid token
      rec[NREP * HD + NREP + h] = lw;
    }
    if (g == 0) {                      // 16 lanes cover this head's 128 dims
      float* rp = rec + h * HD + d16 * 8;
      *(float4*)rp = make_float4(acc[h][0], acc[h][1], acc[h][2], acc[h][3]);
      *(float4*)(rp + 4) = make_float4(acc[h][4], acc[h][5], acc[h][6], acc[h][7]);
    }
  }
}

// ---------------------------------------------------------------------------
// Merge split partials. grid = (KVH, BATCH), block = 256.
// ---------------------------------------------------------------------------
__global__ __launch_bounds__(256) void attn_combine(
    const float* __restrict__ part, float* __restrict__ out) {
  const int kvh = blockIdx.x;
  const int b   = blockIdx.y;
  const int tid = threadIdx.x;
  const float* base = part + ((size_t)b * KVH + kvh) * NSPLITS * REC;

  __shared__ float w_sh[NSPLITS][NREP];
  __shared__ float L_sh[NREP];

  if (tid < NREP) {
    const int h = tid;
    float M = -INFINITY;
    for (int s = 0; s < NSPLITS; ++s)
      M = fmaxf(M, base[s * REC + NREP * HD + h]);
    float L = 0.f;
    for (int s = 0; s < NSPLITS; ++s) {
      float m = base[s * REC + NREP * HD + h];
      float l = base[s * REC + NREP * HD + NREP + h];
      float w = (l > 0.f) ? __expf(m - M) : 0.f;
      w_sh[s][h] = w;
      L += l * w;
    }
    L_sh[h] = L;
  }
  __syncthreads();

  for (int o = tid; o < NREP * HD; o += 256) {
    int h = o >> 7, d = o & 127;
    float s = 0.f;
    for (int sp = 0; sp < NSPLITS; ++sp) {
      float w = w_sh[sp][h];
      if (w > 0.f) s += w * base[sp * REC + o];
    }
    out[((size_t)b * NH + kvh * NREP + h) * HD + d] = s / L_sh[h];
  }
}

// ---------------------------------------------------------------------------
extern "C" void kernel_launch(void* const* d_in, const int* in_sizes, int n_in,
                              void* d_out, int out_size, void* d_ws, size_t ws_size,
                              hipStream_t stream) {
  const float* q = (const float*)d_in[0];
  const float* k = (const float*)d_in[1];
  const float* v = (const float*)d_in[2];
  const float* k_cache = (const float*)d_in[3];  // READ-ONLY: scatter is virtual
  const float* v_cache = (const float*)d_in[4];  // READ-ONLY: scatter is virtual
  const int* block_tables = (const int*)d_in[5];
  const int* context_lens = (const int*)d_in[6];
  const int* slot_mapping = (const int*)d_in[7];
  float* out  = (float*)d_out;
  float* part = (float*)d_ws;   // needs 16*8*32*520*4 = 8.5 MB

  dim3 grid(NSPLITS / 4, KVH, BATCH);
  attn_decode<<<grid, 256, 0, stream>>>(q, k, v, k_cache, v_cache,
                                        block_tables, context_lens,
                                        slot_mapping, part);
  attn_combine<<<dim3(KVH, BATCH), 256, 0, stream>>>(part, out);
}